// Round 2
// baseline (751.537 us; speedup 1.0000x reference)
//
#include <hip/hip_runtime.h>
#include <hip/hip_bf16.h>
#include <stdint.h>

// ---- problem constants ----
#define TT        8192          // tokens = B*S
#define HD        1024          // hidden
#define FD        2048          // intermediate
#define NE        8             // routed experts
#define CAPE      2048          // capacity per expert
#define NASS      (TT*2)        // assignments (top-2)
#define ROWS_RT   (NE*CAPE)     // 16384 routed slot rows
#define ROWS_ALL  (ROWS_RT+TT)  // 24576 (routed slots + shared tokens)

using bf16x8 = __attribute__((ext_vector_type(8))) short;
using f32x4  = __attribute__((ext_vector_type(4))) float;

__device__ __forceinline__ float bf2f(unsigned short h){ return __uint_as_float(((unsigned)h)<<16); }
__device__ __forceinline__ unsigned short f2bf(float f){
  unsigned u = __float_as_uint(f);
  return (unsigned short)((u + 0x7fffu + ((u>>16)&1u)) >> 16);   // RNE
}
__device__ __forceinline__ void gl_lds16(const void* g, void* l){
  __builtin_amdgcn_global_load_lds((const __attribute__((address_space(1))) unsigned*)g,
                                   (__attribute__((address_space(3))) unsigned*)l, 16, 0, 0);
}

// ===================== 1. RMSNorm + gate (softmax/top-2) =====================
__global__ void k_rms_gate(const float* __restrict__ x, const float* __restrict__ rmsw,
                           const float* __restrict__ gw,
                           unsigned short* __restrict__ xn,
                           int* __restrict__ tkidx, float* __restrict__ tkw)
{
  __shared__ __align__(16) float sh[HD];
  __shared__ float red[4];
  __shared__ float lg[NE];
  const int t = blockIdx.x, tid = threadIdx.x;
  float4 v = ((const float4*)(x + (size_t)t*HD))[tid];
  float ss = v.x*v.x + v.y*v.y + v.z*v.z + v.w*v.w;
  #pragma unroll
  for (int s=32; s; s>>=1) ss += __shfl_down(ss, s);
  if ((tid&63)==0) red[tid>>6] = ss;
  __syncthreads();
  float inv = 1.0f / sqrtf((red[0]+red[1]+red[2]+red[3]) * (1.0f/HD) + 1e-6f);
  float4 w4 = ((const float4*)rmsw)[tid];
  float n0 = v.x*inv*w4.x, n1 = v.y*inv*w4.y, n2 = v.z*inv*w4.z, n3 = v.w*inv*w4.w;
  sh[tid*4+0]=n0; sh[tid*4+1]=n1; sh[tid*4+2]=n2; sh[tid*4+3]=n3;
  ushort4 q; q.x=f2bf(n0); q.y=f2bf(n1); q.z=f2bf(n2); q.w=f2bf(n3);
  ((ushort4*)(xn + (size_t)t*HD))[tid] = q;
  __syncthreads();
  // logits: 32 lanes per expert
  const int e = tid>>5, l = tid&31;
  const float* g = gw + e*HD;
  float acc = 0.f;
  #pragma unroll 4
  for (int c=l; c<HD; c+=32) acc += sh[c]*g[c];
  #pragma unroll
  for (int s=16; s; s>>=1) acc += __shfl_xor(acc, s);
  if (l==0) lg[e] = acc;
  __syncthreads();
  if (tid==0){
    float mx = lg[0];
    #pragma unroll
    for (int i=1;i<NE;i++) mx = fmaxf(mx, lg[i]);
    float p[NE]; float Z=0.f;
    #pragma unroll
    for (int i=0;i<NE;i++){ p[i]=expf(lg[i]-mx); Z+=p[i]; }
    int i0=0;
    #pragma unroll
    for (int i=1;i<NE;i++) if (p[i] > p[i0]) i0=i;      // ties -> lowest index (strict >)
    int i1=(i0==0)?1:0;
    #pragma unroll
    for (int i=0;i<NE;i++) if (i!=i0 && p[i] > p[i1]) i1=i;
    float s0=p[i0]/Z, s1=p[i1]/Z;
    float d = s0+s1+1e-20f;
    tkidx[2*t]=i0; tkidx[2*t+1]=i1;
    tkw[2*t]=s0/d; tkw[2*t+1]=s1/d;
  }
}

// ===================== 2. stable capacity-limited dispatch =====================
// 8 waves, wave e scans all assignments in order; rank = stable position within expert.
__global__ void k_dispatch(const int* __restrict__ tkidx,
                           int* __restrict__ tok, int* __restrict__ smap)
{
  const int e = threadIdx.x>>6, lane = threadIdx.x&63;
  int base = 0;
  for (int c=0; c<NASS; c+=256){
    int v0=tkidx[c+lane], v1=tkidx[c+64+lane], v2=tkidx[c+128+lane], v3=tkidx[c+192+lane];
    #pragma unroll
    for (int u=0; u<4; ++u){
      int v = (u==0)?v0:(u==1)?v1:(u==2)?v2:v3;
      int a0 = c + u*64;
      unsigned long long m = __ballot(v==e);
      if (v==e){
        int slot = base + __popcll(m & ((1ull<<lane)-1ull));
        int a = a0 + lane;
        smap[a] = (slot < CAPE) ? (e*CAPE + slot) : -1;
        if (slot < CAPE) tok[e*CAPE + slot] = a>>1;
      }
      base += __popcll(m);
    }
  }
  for (int s = base + lane; s < CAPE; s += 64) tok[e*CAPE + s] = 0;  // pads (never referenced)
}

// ===================== 3. fp32 -> bf16 weight conversion =====================
__global__ void k_cvt3(const float* __restrict__ a, const float* __restrict__ b,
                       const float* __restrict__ c,
                       unsigned short* __restrict__ da, unsigned short* __restrict__ db,
                       unsigned short* __restrict__ dc, int n4)
{
  int i = blockIdx.x*blockDim.x + threadIdx.x;
  const int st = gridDim.x*blockDim.x;
  for (; i<n4; i+=st){
    float4 v; ushort4 o;
    v = ((const float4*)a)[i]; o.x=f2bf(v.x); o.y=f2bf(v.y); o.z=f2bf(v.z); o.w=f2bf(v.w); ((ushort4*)da)[i]=o;
    v = ((const float4*)b)[i]; o.x=f2bf(v.x); o.y=f2bf(v.y); o.z=f2bf(v.z); o.w=f2bf(v.w); ((ushort4*)db)[i]=o;
    v = ((const float4*)c)[i]; o.x=f2bf(v.x); o.y=f2bf(v.y); o.z=f2bf(v.z); o.w=f2bf(v.w); ((ushort4*)dc)[i]=o;
  }
}

// ===================== 4. gate+up fused GEMM, silu(g)*u epilogue =====================
// BM=128 (rows), BN=64 (F), BK=64.  grid = (F/64, 128 routed tiles + 64 shared tiles)
// LDS (ushort units): X[128][64] @0, Wg[64][64] @8192, Wu[64][64] @12288.  XOR swizzle chunk^=(row&7).
__global__ __launch_bounds__(256) void k_gateup(
    const unsigned short* __restrict__ xn,
    const unsigned short* __restrict__ wgb, const unsigned short* __restrict__ wub,
    const unsigned short* __restrict__ swgb, const unsigned short* __restrict__ swub,
    const int* __restrict__ tok, unsigned short* __restrict__ Aws)
{
  __shared__ __align__(16) unsigned short lds[16384];  // 32 KiB
  const int ft = blockIdx.x, my = blockIdx.y, tid = threadIdx.x;
  const bool routed = my < 128;
  const int rowbase = my*128;               // == e*CAPE + mt*128 for routed
  const int m0 = routed ? 0 : (my-128)*128; // shared token tile base
  const unsigned short* pwg = routed ? (wgb + (size_t)(my>>4)*FD*HD) : swgb;
  const unsigned short* pwu = routed ? (wub + (size_t)(my>>4)*FD*HD) : swub;

  const unsigned short* src[8];
  #pragma unroll
  for (int i=0;i<8;i++){
    int chunk = i*256 + tid;
    int cc = chunk & 7;
    if (i<4){
      int row = chunk>>3;
      int scol = cc ^ (row&7);
      int grow = routed ? tok[rowbase + row] : (m0 + row);
      src[i] = xn + (size_t)grow*HD + scol*8;
    } else {
      int row = (chunk - ((i<6)?1024:1536)) >> 3;
      int scol = cc ^ (row&7);
      const unsigned short* wp = (i<6) ? pwg : pwu;
      src[i] = wp + (size_t)(ft*64+row)*HD + scol*8;
    }
  }

  const int wave = tid>>6, lane = tid&63;
  const int wr = wave>>1, wcid = wave&1;
  const int r15 = lane&15, hi = lane>>4;

  f32x4 aG[4][2], aU[4][2];
  #pragma unroll
  for (int mi=0;mi<4;++mi)
    #pragma unroll
    for (int ni=0;ni<2;++ni){ aG[mi][ni]=(f32x4){0.f,0.f,0.f,0.f}; aU[mi][ni]=(f32x4){0.f,0.f,0.f,0.f}; }

  for (int kt=0; kt<16; ++kt){
    #pragma unroll
    for (int i=0;i<8;i++) gl_lds16(src[i] + kt*64, &lds[(unsigned)(i*256+tid)*8]);
    __syncthreads();
    #pragma unroll
    for (int ks=0; ks<2; ++ks){
      bf16x8 af[4], bg[2], bu[2];
      #pragma unroll
      for (int mi=0;mi<4;++mi){
        int row = wr*64 + mi*16 + r15;
        int ch = (ks*4 + hi) ^ (row&7);
        af[mi] = *(const bf16x8*)&lds[row*64 + ch*8];
      }
      #pragma unroll
      for (int ni=0;ni<2;++ni){
        int row = wcid*32 + ni*16 + r15;
        int ch = (ks*4 + hi) ^ (row&7);
        bg[ni] = *(const bf16x8*)&lds[8192  + row*64 + ch*8];
        bu[ni] = *(const bf16x8*)&lds[12288 + row*64 + ch*8];
      }
      #pragma unroll
      for (int mi=0;mi<4;++mi)
        #pragma unroll
        for (int ni=0;ni<2;++ni){
          aG[mi][ni] = __builtin_amdgcn_mfma_f32_16x16x32_bf16(af[mi], bg[ni], aG[mi][ni], 0,0,0);
          aU[mi][ni] = __builtin_amdgcn_mfma_f32_16x16x32_bf16(af[mi], bu[ni], aU[mi][ni], 0,0,0);
        }
    }
    __syncthreads();
  }
  // epilogue: act = silu(g)*u -> LDS [128][64] -> vectorized store
  #pragma unroll
  for (int mi=0;mi<4;++mi)
    #pragma unroll
    for (int ni=0;ni<2;++ni)
      #pragma unroll
      for (int j=0;j<4;++j){
        float g = aG[mi][ni][j], u = aU[mi][ni][j];
        float act = (g / (1.0f + expf(-g))) * u;
        int row = wr*64 + mi*16 + hi*4 + j;
        int col = wcid*32 + ni*16 + r15;
        lds[row*64 + col] = f2bf(act);
      }
  __syncthreads();
  const size_t obase = (size_t)(routed ? rowbase : (ROWS_RT + m0)) * FD + (size_t)ft*64;
  #pragma unroll
  for (int i=0;i<4;i++){
    int chunk = i*256 + tid;
    int row = chunk>>3, cc = chunk&7;
    *(uint4*)&Aws[obase + (size_t)row*FD + cc*8] = *(const uint4*)&lds[chunk*8];
  }
}

// ===================== 5. down-proj GEMM =====================
// BM=128, BN=128 (H), BK=64 over K=F=2048. grid = (H/128, 192). rows: slots then shared.
__global__ __launch_bounds__(256) void k_down(
    const unsigned short* __restrict__ Aws,
    const unsigned short* __restrict__ wdb, const unsigned short* __restrict__ swdb,
    unsigned short* __restrict__ Yws)
{
  __shared__ __align__(16) unsigned short lds[16384];  // A[128][64]@0, W[128][64]@8192
  const int nt = blockIdx.x, my = blockIdx.y, tid = threadIdx.x;
  const bool routed = my < 128;
  const int rowbase = my*128;  // works for shared too (16384 = 128*128)
  const unsigned short* wsel = routed ? (wdb + (size_t)(my>>4)*HD*FD) : swdb;

  const unsigned short* src[8];
  #pragma unroll
  for (int i=0;i<8;i++){
    int chunk = i*256 + tid;
    int row = (chunk & 1023) >> 3, cc = chunk & 7;
    int scol = cc ^ (row&7);
    if (i<4) src[i] = Aws  + (size_t)(rowbase + row)*FD + scol*8;
    else     src[i] = wsel + (size_t)(nt*128 + row)*FD + scol*8;
  }

  const int wave = tid>>6, lane = tid&63;
  const int wr = wave>>1, wcid = wave&1;
  const int r15 = lane&15, hi = lane>>4;

  f32x4 acc[4][4];
  #pragma unroll
  for (int mi=0;mi<4;++mi)
    #pragma unroll
    for (int ni=0;ni<4;++ni) acc[mi][ni]=(f32x4){0.f,0.f,0.f,0.f};

  for (int kt=0; kt<32; ++kt){
    #pragma unroll
    for (int i=0;i<8;i++) gl_lds16(src[i] + kt*64, &lds[(unsigned)(i*256+tid)*8]);
    __syncthreads();
    #pragma unroll
    for (int ks=0; ks<2; ++ks){
      bf16x8 af[4], bf[4];
      #pragma unroll
      for (int mi=0;mi<4;++mi){
        int row = wr*64 + mi*16 + r15;
        int ch = (ks*4 + hi) ^ (row&7);
        af[mi] = *(const bf16x8*)&lds[row*64 + ch*8];
      }
      #pragma unroll
      for (int ni=0;ni<4;++ni){
        int row = wcid*64 + ni*16 + r15;
        int ch = (ks*4 + hi) ^ (row&7);
        bf[ni] = *(const bf16x8*)&lds[8192 + row*64 + ch*8];
      }
      #pragma unroll
      for (int mi=0;mi<4;++mi)
        #pragma unroll
        for (int ni=0;ni<4;++ni)
          acc[mi][ni] = __builtin_amdgcn_mfma_f32_16x16x32_bf16(af[mi], bf[ni], acc[mi][ni], 0,0,0);
    }
    __syncthreads();
  }
  // epilogue -> LDS [128][128] bf16 -> vector stores
  #pragma unroll
  for (int mi=0;mi<4;++mi)
    #pragma unroll
    for (int ni=0;ni<4;++ni)
      #pragma unroll
      for (int j=0;j<4;++j){
        int row = wr*64 + mi*16 + hi*4 + j;
        int col = wcid*64 + ni*16 + r15;
        lds[row*128 + col] = f2bf(acc[mi][ni][j]);
      }
  __syncthreads();
  const size_t obase = (size_t)rowbase*HD + (size_t)nt*128;
  #pragma unroll
  for (int i=0;i<8;i++){
    int chunk = i*256 + tid;
    int row = chunk>>4, cc = chunk&15;
    *(uint4*)&Yws[obase + (size_t)row*HD + cc*8] = *(const uint4*)&lds[chunk*8];
  }
}

// ===================== 6. combine: shared + weighted routed gather =====================
__global__ void k_combine(const unsigned short* __restrict__ Yws,
                          const int* __restrict__ smap, const float* __restrict__ tkw,
                          float* __restrict__ out)
{
  const int t = blockIdx.x, tid = threadIdx.x;
  const int s0 = smap[2*t], s1 = smap[2*t+1];
  const float w0 = tkw[2*t], w1 = tkw[2*t+1];
  ushort4 ys = ((const ushort4*)(Yws + (size_t)(ROWS_RT + t)*HD))[tid];
  float r0 = bf2f(ys.x), r1 = bf2f(ys.y), r2 = bf2f(ys.z), r3 = bf2f(ys.w);
  if (s0 >= 0){
    ushort4 a = ((const ushort4*)(Yws + (size_t)s0*HD))[tid];
    r0 += w0*bf2f(a.x); r1 += w0*bf2f(a.y); r2 += w0*bf2f(a.z); r3 += w0*bf2f(a.w);
  }
  if (s1 >= 0){
    ushort4 a = ((const ushort4*)(Yws + (size_t)s1*HD))[tid];
    r0 += w1*bf2f(a.x); r1 += w1*bf2f(a.y); r2 += w1*bf2f(a.z); r3 += w1*bf2f(a.w);
  }
  float4 o; o.x=r0; o.y=r1; o.z=r2; o.w=r3;
  ((float4*)(out + (size_t)t*HD))[tid] = o;
  if (t==0 && tid==0) out[(size_t)TT*HD] = 0.0f;   // aux_loss
}

// ===================== launch =====================
// Workspace layout (aliased, peak ~220.3 MiB):
//   region A [0, 48 MiB): xn (16 MiB) + wgb (32 MiB) during rms/gateup;
//                         REUSED as Yws (48 MiB) by k_down/k_combine (xn,wgb dead by then)
//   [ 48, 80)  wub      [ 80,112) wdb      [112,124) shared weights (3x4 MiB)
//   [124,220)  Aws (96 MiB)                [220, +256 KiB) routing tables
extern "C" void kernel_launch(void* const* d_in, const int* in_sizes, int n_in,
                              void* d_out, int out_size, void* d_ws, size_t ws_size,
                              hipStream_t stream)
{
  const float* x    = (const float*)d_in[0];
  const float* rmsw = (const float*)d_in[1];
  const float* gw   = (const float*)d_in[2];
  const float* wg   = (const float*)d_in[3];
  const float* wu   = (const float*)d_in[4];
  const float* wd   = (const float*)d_in[5];
  const float* swg  = (const float*)d_in[6];
  const float* swu  = (const float*)d_in[7];
  const float* swd  = (const float*)d_in[8];
  float* out = (float*)d_out;

  char* ws = (char*)d_ws;
  unsigned short* xn   = (unsigned short*)(ws + 0);            // 16 MiB   (dead after k_gateup)
  unsigned short* wgb  = (unsigned short*)(ws + 16777216);     // 32 MiB   (dead after k_gateup)
  unsigned short* Yws  = (unsigned short*)(ws + 0);            // 48 MiB   ALIASES xn+wgb
  unsigned short* wub  = (unsigned short*)(ws + 50331648);     // 32 MiB
  unsigned short* wdb  = (unsigned short*)(ws + 83886080);     // 32 MiB
  unsigned short* swgb = (unsigned short*)(ws + 117440512);    // 4 MiB
  unsigned short* swub = (unsigned short*)(ws + 121634816);    // 4 MiB
  unsigned short* swdb = (unsigned short*)(ws + 125829120);    // 4 MiB
  unsigned short* Aws  = (unsigned short*)(ws + 130023424);    // 96 MiB  [24576][2048]
  int*   tkidx = (int*)  (ws + 230686720);                     // 64 KiB
  float* tkw   = (float*)(ws + 230752256);                     // 64 KiB
  int*   tok   = (int*)  (ws + 230817792);                     // 64 KiB
  int*   smap  = (int*)  (ws + 230883328);                     // 64 KiB   (end ~220.3 MiB)

  k_rms_gate<<<dim3(TT), dim3(256), 0, stream>>>(x, rmsw, gw, xn, tkidx, tkw);
  k_dispatch<<<dim3(1), dim3(512), 0, stream>>>(tkidx, tok, smap);
  k_cvt3<<<dim3(1024), dim3(256), 0, stream>>>(wg, wu, wd, wgb, wub, wdb, (NE*FD*HD)/4);
  k_cvt3<<<dim3(256), dim3(256), 0, stream>>>(swg, swu, swd, swgb, swub, swdb, (FD*HD)/4);
  k_gateup<<<dim3(FD/64, 192), dim3(256), 0, stream>>>(xn, wgb, wub, swgb, swub, tok, Aws);
  k_down<<<dim3(HD/128, 192), dim3(256), 0, stream>>>(Aws, wdb, swdb, Yws);
  k_combine<<<dim3(TT), dim3(256), 0, stream>>>(Yws, smap, tkw, out);
}

// Round 3
// 695.598 us; speedup vs baseline: 1.0804x; 1.0804x over previous
//
#include <hip/hip_runtime.h>
#include <hip/hip_bf16.h>
#include <stdint.h>

// ---- problem constants ----
#define TT        8192          // tokens = B*S
#define HD        1024          // hidden
#define FD        2048          // intermediate
#define NE        8             // routed experts
#define CAPE      2048          // capacity per expert
#define NASS      (TT*2)        // assignments (top-2)
#define ROWS_RT   (NE*CAPE)     // 16384 routed slot rows
#define ROWS_ALL  (ROWS_RT+TT)  // 24576

using bf16x8 = __attribute__((ext_vector_type(8))) short;
using f32x4  = __attribute__((ext_vector_type(4))) float;

__device__ __forceinline__ float bf2f(unsigned short h){ return __uint_as_float(((unsigned)h)<<16); }
__device__ __forceinline__ unsigned short f2bf(float f){
  unsigned u = __float_as_uint(f);
  return (unsigned short)((u + 0x7fffu + ((u>>16)&1u)) >> 16);   // RNE
}
__device__ __forceinline__ void gl_lds16(const void* g, void* l){
  __builtin_amdgcn_global_load_lds((const __attribute__((address_space(1))) unsigned*)g,
                                   (__attribute__((address_space(3))) unsigned*)l, 16, 0, 0);
}

// ===================== 1. RMSNorm + gate (softmax/top-2) =====================
__global__ void k_rms_gate(const float* __restrict__ x, const float* __restrict__ rmsw,
                           const float* __restrict__ gw,
                           unsigned short* __restrict__ xn,
                           int* __restrict__ tkidx, float* __restrict__ tkw)
{
  __shared__ __align__(16) float sh[HD];
  __shared__ float red[4];
  __shared__ float lg[NE];
  const int t = blockIdx.x, tid = threadIdx.x;
  float4 v = ((const float4*)(x + (size_t)t*HD))[tid];
  float ss = v.x*v.x + v.y*v.y + v.z*v.z + v.w*v.w;
  #pragma unroll
  for (int s=32; s; s>>=1) ss += __shfl_down(ss, s);
  if ((tid&63)==0) red[tid>>6] = ss;
  __syncthreads();
  float inv = 1.0f / sqrtf((red[0]+red[1]+red[2]+red[3]) * (1.0f/HD) + 1e-6f);
  float4 w4 = ((const float4*)rmsw)[tid];
  float n0 = v.x*inv*w4.x, n1 = v.y*inv*w4.y, n2 = v.z*inv*w4.z, n3 = v.w*inv*w4.w;
  sh[tid*4+0]=n0; sh[tid*4+1]=n1; sh[tid*4+2]=n2; sh[tid*4+3]=n3;
  ushort4 q; q.x=f2bf(n0); q.y=f2bf(n1); q.z=f2bf(n2); q.w=f2bf(n3);
  ((ushort4*)(xn + (size_t)t*HD))[tid] = q;
  __syncthreads();
  const int e = tid>>5, l = tid&31;
  const float* g = gw + e*HD;
  float acc = 0.f;
  #pragma unroll 4
  for (int c=l; c<HD; c+=32) acc += sh[c]*g[c];
  #pragma unroll
  for (int s=16; s; s>>=1) acc += __shfl_xor(acc, s);
  if (l==0) lg[e] = acc;
  __syncthreads();
  if (tid==0){
    float mx = lg[0];
    #pragma unroll
    for (int i=1;i<NE;i++) mx = fmaxf(mx, lg[i]);
    float p[NE]; float Z=0.f;
    #pragma unroll
    for (int i=0;i<NE;i++){ p[i]=expf(lg[i]-mx); Z+=p[i]; }
    int i0=0;
    #pragma unroll
    for (int i=1;i<NE;i++) if (p[i] > p[i0]) i0=i;
    int i1=(i0==0)?1:0;
    #pragma unroll
    for (int i=0;i<NE;i++) if (i!=i0 && p[i] > p[i1]) i1=i;
    float s0=p[i0]/Z, s1=p[i1]/Z;
    float d = s0+s1+1e-20f;
    tkidx[2*t]=i0; tkidx[2*t+1]=i1;
    tkw[2*t]=s0/d; tkw[2*t+1]=s1/d;
  }
}

// ===================== 2. stable capacity-limited dispatch =====================
__global__ void k_dispatch(const int* __restrict__ tkidx,
                           int* __restrict__ tok, int* __restrict__ smap)
{
  const int e = threadIdx.x>>6, lane = threadIdx.x&63;
  int base = 0;
  for (int c=0; c<NASS; c+=256){
    int v0=tkidx[c+lane], v1=tkidx[c+64+lane], v2=tkidx[c+128+lane], v3=tkidx[c+192+lane];
    #pragma unroll
    for (int u=0; u<4; ++u){
      int v = (u==0)?v0:(u==1)?v1:(u==2)?v2:v3;
      int a0 = c + u*64;
      unsigned long long m = __ballot(v==e);
      if (v==e){
        int slot = base + __popcll(m & ((1ull<<lane)-1ull));
        int a = a0 + lane;
        smap[a] = (slot < CAPE) ? (e*CAPE + slot) : -1;
        if (slot < CAPE) tok[e*CAPE + slot] = a>>1;
      }
      base += __popcll(m);
    }
  }
  for (int s = base + lane; s < CAPE; s += 64) tok[e*CAPE + s] = 0;
}

// ===================== 3. fp32 -> bf16 weight conversion =====================
__global__ void k_cvt3(const float* __restrict__ a, const float* __restrict__ b,
                       const float* __restrict__ c,
                       unsigned short* __restrict__ da, unsigned short* __restrict__ db,
                       unsigned short* __restrict__ dc, int n4)
{
  int i = blockIdx.x*blockDim.x + threadIdx.x;
  const int st = gridDim.x*blockDim.x;
  for (; i<n4; i+=st){
    float4 v; ushort4 o;
    v = ((const float4*)a)[i]; o.x=f2bf(v.x); o.y=f2bf(v.y); o.z=f2bf(v.z); o.w=f2bf(v.w); ((ushort4*)da)[i]=o;
    v = ((const float4*)b)[i]; o.x=f2bf(v.x); o.y=f2bf(v.y); o.z=f2bf(v.z); o.w=f2bf(v.w); ((ushort4*)db)[i]=o;
    v = ((const float4*)c)[i]; o.x=f2bf(v.x); o.y=f2bf(v.y); o.z=f2bf(v.z); o.w=f2bf(v.w); ((ushort4*)dc)[i]=o;
  }
}

// =====================================================================
// 256x256 8-phase GEMM template (T2+T3+T4+T5), BK=64, 8 waves (2Mx4N).
// LDS 128 KiB: A slot0 @0, A slot1 @16384, B slot0 @32768, B slot1 @49152 (ushorts).
// Phase p of K-tile t: ds_read quadrant (mq,nq); stage one 16KiB half-tile;
// barrier; lgkmcnt(0); 16 MFMA; counted vmcnt gate at ph1(6)/ph4(8); barrier.
// Stage schedule (tile t): ph1: A-q1(t+1)  ph2: B-e1(t+1)  ph3: A-q0(t+2)  ph4: B-e0(t+2)
//   A-q0 = row blocks {0-63,128-191}; A-q1 = {64-127,192-255}
//   B-e0 = vrows {0-31,64-95,128-159,192-223}; B-e1 = +32
// Gate derivation (FIFO, 2 loads/phase): ph1 reads need stages aged >= 8 issues back -> vmcnt(8)
// at end of ph4; ph2 reads need B-e1(t) staged ph2(t-1), 6 issues back -> vmcnt(6) end of ph1.
// =====================================================================

#define GEMM_PHASE(MQ, NQ, STG, GATE) do{                                  \
    const unsigned short* As_ = &lds[(t&1)*16384];                         \
    const unsigned short* Bs_ = &lds[32768 + (t&1)*16384];                 \
    bf16x8 afr[4][2], bfr[2][2];                                           \
    _Pragma("unroll") for (int mi=0;mi<4;++mi){                            \
      int row_ = wr*128 + MQ*64 + mi*16 + r15;                             \
      _Pragma("unroll") for (int ks=0;ks<2;++ks)                           \
        afr[mi][ks] = *(const bf16x8*)&As_[row_*64 + ch[ks]*8];            \
    }                                                                      \
    _Pragma("unroll") for (int ni=0;ni<2;++ni){                            \
      int vr_ = wc*64 + NQ*32 + ni*16 + r15;                               \
      _Pragma("unroll") for (int ks=0;ks<2;++ks)                           \
        bfr[ni][ks] = *(const bf16x8*)&Bs_[vr_*64 + ch[ks]*8];             \
    }                                                                      \
    STG;                                                                   \
    __builtin_amdgcn_s_barrier();                                          \
    asm volatile("s_waitcnt lgkmcnt(0)" ::: "memory");                     \
    __builtin_amdgcn_sched_barrier(0);                                     \
    __builtin_amdgcn_s_setprio(1);                                         \
    _Pragma("unroll") for (int ks=0;ks<2;++ks)                             \
      _Pragma("unroll") for (int mi=0;mi<4;++mi)                           \
        _Pragma("unroll") for (int ni=0;ni<2;++ni)                         \
          acc[MQ][NQ][mi][ni] = __builtin_amdgcn_mfma_f32_16x16x32_bf16(   \
              afr[mi][ks], bfr[ni][ks], acc[MQ][NQ][mi][ni], 0,0,0);       \
    __builtin_amdgcn_s_setprio(0);                                         \
    __builtin_amdgcn_sched_barrier(0);                                     \
    GATE;                                                                  \
    __builtin_amdgcn_s_barrier();                                          \
    __builtin_amdgcn_sched_barrier(0);                                     \
  }while(0)

#define GATE6 asm volatile("s_waitcnt vmcnt(6)" ::: "memory")
#define GATE8 asm volatile("s_waitcnt vmcnt(8)" ::: "memory")
#define NOGATE ((void)0)

// ===================== 4. gate+up fused 256^2 GEMM =====================
// grid (16 f-tiles, 96 M-tiles), 512 thr. B virtual rows interleave Wg/Wu per
// 32-row group so acc[..][0][..]=g, acc[..][1][..]=u for the SAME f per lane.
#define GU_NT 16
__global__ __launch_bounds__(512) void k_gateup256(
    const unsigned short* __restrict__ xn,
    const unsigned short* __restrict__ wgb, const unsigned short* __restrict__ wub,
    const unsigned short* __restrict__ swgb, const unsigned short* __restrict__ swub,
    const int* __restrict__ tok, unsigned short* __restrict__ Aws)
{
  __shared__ __align__(16) unsigned short lds[65536];   // 128 KiB
  const int ft = blockIdx.x, my = blockIdx.y, tid = threadIdx.x;
  const bool routed = my < 64;
  const int rowbase = my*256;
  const int shbase  = (my-64)*256;
  const unsigned short* pg = routed ? (wgb + (size_t)(my>>3)*FD*HD) : swgb;
  const unsigned short* pu = routed ? (wub + (size_t)(my>>3)*FD*HD) : swub;

  // per-thread stage sources
  const int r0 = tid>>3, cc = tid&7;
  const int swA = cc ^ (r0&7);
  const unsigned short* asrc[4];
  #pragma unroll
  for (int i=0;i<4;i++){
    int row = r0 + i*64;
    int grow = routed ? tok[rowbase + row] : (shbase + row);
    asrc[i] = xn + (size_t)grow*HD + swA*8;
  }
  const unsigned short* bsrc[2][2];
  int bdst[2][2];
  #pragma unroll
  for (int e=0;e<2;e++)
    #pragma unroll
    for (int j=0;j<2;j++){
      int vrow = e*32 + (r0&31) + ((tid>>8)<<6) + j*128;
      int fr = ft*128 + (vrow>>6)*32 + (vrow&31);
      const unsigned short* wb = (vrow&32) ? pu : pg;
      bsrc[e][j] = wb + (size_t)fr*HD + (cc ^ (vrow&7))*8;
      bdst[e][j] = vrow*64 + cc*8;
    }

  auto STAGE_A = [&](int kind /*0=q1,2=q0*/, int tt){
    int slot = tt&1, kk = (tt & (GU_NT-1))*64;
    int rb0 = (kind==0) ? 1 : 0;
    #pragma unroll
    for (int j=0;j<2;j++){
      int ib = rb0 + j*2;
      gl_lds16(asrc[ib] + kk, &lds[slot*16384 + ib*4096 + tid*8]);
    }
  };
  auto STAGE_B = [&](int e, int tt){
    int slot = tt&1, kk = (tt & (GU_NT-1))*64;
    #pragma unroll
    for (int j=0;j<2;j++)
      gl_lds16(bsrc[e][j] + kk, &lds[32768 + slot*16384 + bdst[e][j]]);
  };

  const int wv = tid>>6, lane = tid&63;
  const int wr = wv>>2, wc = wv&3;
  const int r15 = lane&15, hi = lane>>4;
  int ch[2]; ch[0] = hi ^ (r15&7); ch[1] = (4+hi) ^ (r15&7);

  f32x4 acc[2][2][4][2] = {};

  // prologue: t0 fully + t1 A-q0,B-e0 (matches steady FIFO pattern)
  STAGE_A(2,0); STAGE_B(0,0); STAGE_A(0,0); STAGE_B(1,0);
  STAGE_A(2,1); STAGE_B(0,1);
  GATE8;
  __builtin_amdgcn_s_barrier();
  __builtin_amdgcn_sched_barrier(0);

  for (int t=0; t<GU_NT; ++t){
    GEMM_PHASE(0,0, STAGE_A(0,t+1), GATE6);
    GEMM_PHASE(0,1, STAGE_B(1,t+1), NOGATE);
    GEMM_PHASE(1,0, STAGE_A(2,t+2), NOGATE);
    GEMM_PHASE(1,1, STAGE_B(0,t+2), GATE8);
  }

  // epilogue: act = silu(g)*u  (g,u same lane: nq=0/1)
  asm volatile("s_waitcnt vmcnt(0) lgkmcnt(0)" ::: "memory");
  __builtin_amdgcn_s_barrier();
  __builtin_amdgcn_sched_barrier(0);
  #pragma unroll
  for (int mq=0;mq<2;++mq)
    #pragma unroll
    for (int mi=0;mi<4;++mi)
      #pragma unroll
      for (int ni=0;ni<2;++ni)
        #pragma unroll
        for (int j=0;j<4;++j){
          float g = acc[mq][0][mi][ni][j], u = acc[mq][1][mi][ni][j];
          float act = (g / (1.0f + expf(-g))) * u;
          int row = wr*128 + mq*64 + mi*16 + hi*4 + j;
          int fl  = wc*32 + ni*16 + r15;
          lds[row*128 + fl] = f2bf(act);
        }
  __syncthreads();
  const size_t gb = (size_t)(routed ? rowbase : (ROWS_RT + shbase)) * FD + (size_t)ft*128;
  #pragma unroll
  for (int i=0;i<8;i++){
    int chunk = i*512 + tid;
    int row = chunk>>4, ccs = chunk&15;
    *(uint4*)&Aws[gb + (size_t)row*FD + ccs*8] = *(const uint4*)&lds[chunk*8];
  }
}

// ===================== 5. down-proj 256^2 GEMM =====================
// grid (4 n-tiles, 96 M-tiles), 512 thr, K=2048 (NT=32)
#define DN_NT 32
__global__ __launch_bounds__(512) void k_down256(
    const unsigned short* __restrict__ Aws,
    const unsigned short* __restrict__ wdb, const unsigned short* __restrict__ swdb,
    unsigned short* __restrict__ Yws)
{
  __shared__ __align__(16) unsigned short lds[65536];
  const int nt = blockIdx.x, my = blockIdx.y, tid = threadIdx.x;
  const bool routed = my < 64;
  const int rowbase = my*256;
  const unsigned short* wsel = routed ? (wdb + (size_t)(my>>3)*HD*FD) : swdb;

  const int r0 = tid>>3, cc = tid&7;
  const int swA = cc ^ (r0&7);
  const unsigned short* asrc[4];
  #pragma unroll
  for (int i=0;i<4;i++)
    asrc[i] = Aws + (size_t)(rowbase + r0 + i*64)*FD + swA*8;
  const unsigned short* bsrc[2][2];
  int bdst[2][2];
  #pragma unroll
  for (int e=0;e<2;e++)
    #pragma unroll
    for (int j=0;j<2;j++){
      int vrow = e*32 + (r0&31) + ((tid>>8)<<6) + j*128;
      bsrc[e][j] = wsel + (size_t)(nt*256 + vrow)*FD + (cc ^ (vrow&7))*8;
      bdst[e][j] = vrow*64 + cc*8;
    }

  auto STAGE_A = [&](int kind, int tt){
    int slot = tt&1, kk = (tt & (DN_NT-1))*64;
    int rb0 = (kind==0) ? 1 : 0;
    #pragma unroll
    for (int j=0;j<2;j++){
      int ib = rb0 + j*2;
      gl_lds16(asrc[ib] + kk, &lds[slot*16384 + ib*4096 + tid*8]);
    }
  };
  auto STAGE_B = [&](int e, int tt){
    int slot = tt&1, kk = (tt & (DN_NT-1))*64;
    #pragma unroll
    for (int j=0;j<2;j++)
      gl_lds16(bsrc[e][j] + kk, &lds[32768 + slot*16384 + bdst[e][j]]);
  };

  const int wv = tid>>6, lane = tid&63;
  const int wr = wv>>2, wc = wv&3;
  const int r15 = lane&15, hi = lane>>4;
  int ch[2]; ch[0] = hi ^ (r15&7); ch[1] = (4+hi) ^ (r15&7);

  f32x4 acc[2][2][4][2] = {};

  STAGE_A(2,0); STAGE_B(0,0); STAGE_A(0,0); STAGE_B(1,0);
  STAGE_A(2,1); STAGE_B(0,1);
  GATE8;
  __builtin_amdgcn_s_barrier();
  __builtin_amdgcn_sched_barrier(0);

  for (int t=0; t<DN_NT; ++t){
    GEMM_PHASE(0,0, STAGE_A(0,t+1), GATE6);
    GEMM_PHASE(0,1, STAGE_B(1,t+1), NOGATE);
    GEMM_PHASE(1,0, STAGE_A(2,t+2), NOGATE);
    GEMM_PHASE(1,1, STAGE_B(0,t+2), GATE8);
  }

  asm volatile("s_waitcnt vmcnt(0) lgkmcnt(0)" ::: "memory");
  __builtin_amdgcn_s_barrier();
  __builtin_amdgcn_sched_barrier(0);
  #pragma unroll
  for (int mq=0;mq<2;++mq)
    #pragma unroll
    for (int nq=0;nq<2;++nq)
      #pragma unroll
      for (int mi=0;mi<4;++mi)
        #pragma unroll
        for (int ni=0;ni<2;++ni)
          #pragma unroll
          for (int j=0;j<4;++j){
            int row = wr*128 + mq*64 + mi*16 + hi*4 + j;
            int col = wc*64 + nq*32 + ni*16 + r15;
            lds[row*256 + col] = f2bf(acc[mq][nq][mi][ni][j]);
          }
  __syncthreads();
  const size_t gb = (size_t)rowbase*HD + (size_t)nt*256;
  #pragma unroll
  for (int i=0;i<16;i++){
    int chunk = i*512 + tid;
    int row = chunk>>5, ccs = chunk&31;
    *(uint4*)&Yws[gb + (size_t)row*HD + ccs*8] = *(const uint4*)&lds[chunk*8];
  }
}

// ===================== 6. combine =====================
__global__ void k_combine(const unsigned short* __restrict__ Yws,
                          const int* __restrict__ smap, const float* __restrict__ tkw,
                          float* __restrict__ out)
{
  const int t = blockIdx.x, tid = threadIdx.x;
  const int s0 = smap[2*t], s1 = smap[2*t+1];
  const float w0 = tkw[2*t], w1 = tkw[2*t+1];
  ushort4 ys = ((const ushort4*)(Yws + (size_t)(ROWS_RT + t)*HD))[tid];
  float r0 = bf2f(ys.x), r1 = bf2f(ys.y), r2 = bf2f(ys.z), r3 = bf2f(ys.w);
  if (s0 >= 0){
    ushort4 a = ((const ushort4*)(Yws + (size_t)s0*HD))[tid];
    r0 += w0*bf2f(a.x); r1 += w0*bf2f(a.y); r2 += w0*bf2f(a.z); r3 += w0*bf2f(a.w);
  }
  if (s1 >= 0){
    ushort4 a = ((const ushort4*)(Yws + (size_t)s1*HD))[tid];
    r0 += w1*bf2f(a.x); r1 += w1*bf2f(a.y); r2 += w1*bf2f(a.z); r3 += w1*bf2f(a.w);
  }
  float4 o; o.x=r0; o.y=r1; o.z=r2; o.w=r3;
  ((float4*)(out + (size_t)t*HD))[tid] = o;
  if (t==0 && tid==0) out[(size_t)TT*HD] = 0.0f;
}

// ===================== launch =====================
// Workspace (aliased, peak ~220.3 MiB): region A [0,48M): xn+wgb then Yws;
// [48,80) wub; [80,112) wdb; [112,124) shared weights; [124,220) Aws; tables after.
extern "C" void kernel_launch(void* const* d_in, const int* in_sizes, int n_in,
                              void* d_out, int out_size, void* d_ws, size_t ws_size,
                              hipStream_t stream)
{
  const float* x    = (const float*)d_in[0];
  const float* rmsw = (const float*)d_in[1];
  const float* gw   = (const float*)d_in[2];
  const float* wg   = (const float*)d_in[3];
  const float* wu   = (const float*)d_in[4];
  const float* wd   = (const float*)d_in[5];
  const float* swg  = (const float*)d_in[6];
  const float* swu  = (const float*)d_in[7];
  const float* swd  = (const float*)d_in[8];
  float* out = (float*)d_out;

  char* ws = (char*)d_ws;
  unsigned short* xn   = (unsigned short*)(ws + 0);            // 16 MiB (dead after gateup)
  unsigned short* wgb  = (unsigned short*)(ws + 16777216);     // 32 MiB (dead after gateup)
  unsigned short* Yws  = (unsigned short*)(ws + 0);            // 48 MiB ALIASES xn+wgb
  unsigned short* wub  = (unsigned short*)(ws + 50331648);     // 32 MiB
  unsigned short* wdb  = (unsigned short*)(ws + 83886080);     // 32 MiB
  unsigned short* swgb = (unsigned short*)(ws + 117440512);    // 4 MiB
  unsigned short* swub = (unsigned short*)(ws + 121634816);    // 4 MiB
  unsigned short* swdb = (unsigned short*)(ws + 125829120);    // 4 MiB
  unsigned short* Aws  = (unsigned short*)(ws + 130023424);    // 96 MiB [24576][2048]
  int*   tkidx = (int*)  (ws + 230686720);
  float* tkw   = (float*)(ws + 230752256);
  int*   tok   = (int*)  (ws + 230817792);
  int*   smap  = (int*)  (ws + 230883328);

  k_rms_gate<<<dim3(TT), dim3(256), 0, stream>>>(x, rmsw, gw, xn, tkidx, tkw);
  k_dispatch<<<dim3(1), dim3(512), 0, stream>>>(tkidx, tok, smap);
  k_cvt3<<<dim3(1024), dim3(256), 0, stream>>>(wg, wu, wd, wgb, wub, wdb, (NE*FD*HD)/4);
  k_cvt3<<<dim3(256), dim3(256), 0, stream>>>(swg, swu, swd, swgb, swub, swdb, (FD*HD)/4);
  k_gateup256<<<dim3(16, 96), dim3(512), 0, stream>>>(xn, wgb, wub, swgb, swub, tok, Aws);
  k_down256<<<dim3(4, 96), dim3(512), 0, stream>>>(Aws, wdb, swdb, Yws);
  k_combine<<<dim3(TT), dim3(256), 0, stream>>>(Yws, smap, tkw, out);
}